// Round 8
// baseline (2380.646 us; speedup 1.0000x reference)
//
#include <hip/hip_runtime.h>
#include <hip/hip_bf16.h>
#include <hip/hip_fp16.h>
#include <math.h>

// x:(2048,3,32,32) f32; idx; w1:(128,3,4,4); b1:(128); w2:(256,128,4,4); b2:(256)
// cb0/cb1/cb2:(512,256); fc1_w:(512,16384); fc1_b:(512); fc2_w:(10,512); fc2_b:(10)
// out: 2048*10 logits ++ loss ++ perplexity = 20482 f32
// Precision: conv1 fp32; conv2 split-f16 MFMA (hi + lo*2^-11; lo*lo term dropped,
// contributes ~5e-8 << 3e-7 budget). VQ screening bf16 MFMA + exact f64 rescore of
// 16 candidates. fc1 bf16 MFMA. fc2 fp32.
// R8 layout fixes (write-amplification): h in slab layout [b][cg][px][8ci] so conv1
// stores are lane-contiguous full granules; fea f32 now [img][px][co] so conv2m
// epilogue emits 64B-granule chunks (16 lanes x 4B contiguous co).

#define CHUNK 256
#define NCH 8

typedef __attribute__((ext_vector_type(8))) short short8;            // 8 bf16
typedef __attribute__((ext_vector_type(8))) _Float16 half8;          // 8 f16
typedef __attribute__((ext_vector_type(8))) unsigned short ushort8v;
typedef __attribute__((ext_vector_type(4))) float f32x4;

__device__ inline unsigned short f2bf(float v) {
    __hip_bfloat16 h = __float2bfloat16(v);   // RNE
    return *reinterpret_cast<unsigned short*>(&h);
}

// ---------------- conv1: fp32; emits split-f16 h, slab layout [b][cg][px][8ci] ----------------
__global__ __launch_bounds__(256) void k_conv1(const float* __restrict__ x,
                                               const float* __restrict__ w1,
                                               const float* __restrict__ b1,
                                               unsigned short* __restrict__ h_hi,
                                               unsigned short* __restrict__ h_lo) {
    __shared__ float xs[3 * 32 * 32];
    int b = blockIdx.x, t = threadIdx.x;
    const float* xb = x + (size_t)b * 3072;
    for (int i = t; i < 768; i += 256)
        ((float4*)xs)[i] = ((const float4*)xb)[i];
    __syncthreads();
    int py = t >> 4, px = t & 15;
    float win[48];
#pragma unroll
    for (int ci = 0; ci < 3; ci++)
#pragma unroll
        for (int ky = 0; ky < 4; ky++) {
            int iy = 2 * py - 1 + ky;
#pragma unroll
            for (int kx = 0; kx < 4; kx++) {
                int ix = 2 * px - 1 + kx;
                bool ok = ((unsigned)iy < 32u) && ((unsigned)ix < 32u);
                win[ci * 16 + ky * 4 + kx] = ok ? xs[ci * 1024 + iy * 32 + ix] : 0.f;
            }
        }
    for (int cg = 0; cg < 16; cg++) {
        ushort8v hi8, lo8;
#pragma unroll
        for (int j = 0; j < 8; j++) {
            int co = cg * 8 + j;
            const float* w = w1 + co * 48;    // wave-uniform -> scalar K$ loads
            float acc = b1[co];
#pragma unroll
            for (int q = 0; q < 48; q++) acc = fmaf(win[q], w[q], acc);
            float v = fmaxf(acc, 0.f);
            __half hh = __float2half(v);
            float hf = __half2float(hh);
            __half ll = __float2half((v - hf) * 2048.0f);   // lo scaled 2^11: normal range
            hi8[j] = __half_as_ushort(hh);
            lo8[j] = __half_as_ushort(ll);
        }
        size_t go = (((size_t)b * 16 + cg) * 256 + t) * 8;   // lane-contiguous 16B stores
        *(ushort8v*)(h_hi + go) = hi8;
        *(ushort8v*)(h_lo + go) = lo8;
    }
}

// ---------------- w2 prep: [co][ci][tap] -> split-f16 [co][tap][ci] ----------------
__global__ __launch_bounds__(256) void k_w2p(const float* __restrict__ w2,
                                             unsigned short* __restrict__ Wh,
                                             unsigned short* __restrict__ Wl) {
    int co = blockIdx.x, t = threadIdx.x;
#pragma unroll
    for (int k = 0; k < 8; k++) {
        int e = t + k * 256;                  // 0..2047
        int ci = e >> 4, tap = e & 15;
        float v = w2[(size_t)co * 2048 + e];
        __half hh = __float2half(v);
        __half ll = __float2half((v - __half2float(hh)) * 2048.0f);
        Wh[(size_t)co * 2048 + tap * 128 + ci] = __half_as_ushort(hh);
        Wl[(size_t)co * 2048 + tap * 128 + ci] = __half_as_ushort(ll);
    }
}

// ---------------- conv2 as split-f16 MFMA im2col GEMM ----------------
// grid (CHUNK, 2): block = (image, 128-co half). M=64 out-px, N=128 co, K=16 taps x 128 ci.
// 3 products: hh + (h_hi*w_lo + h_lo*w_hi)*2^-11 (lo*lo dropped, ~5e-8).
__global__ __launch_bounds__(256, 2) void k_conv2m(const unsigned short* __restrict__ h_hi,
                                                   const unsigned short* __restrict__ h_lo,
                                                   const unsigned short* __restrict__ Wh,
                                                   const unsigned short* __restrict__ Wl,
                                                   const float* __restrict__ b2,
                                                   float* __restrict__ fea,
                                                   unsigned short* __restrict__ fea_bf) {
    __shared__ unsigned short Ah[64 * 40], Al[64 * 40], Bh[128 * 40], Bl[128 * 40];  // 30 KB
    int img = blockIdx.x, nh = blockIdx.y, t = threadIdx.x;
    int L = t & 63, w = t >> 6;
    int quad = L >> 4, lc = L & 15;
    int mw = (w >> 1) * 32, nw = (w & 1) * 64;
    int am = t >> 2, as = t & 3;              // A staging: out-px row, 8-ci segment (slab)
    int ayo = am >> 3, axo = am & 7;
    int bn = t >> 1, bp = t & 1;              // B staging: co row, half
    f32x4 a0[2][4], a1[2][4];
#pragma unroll
    for (int i = 0; i < 2; i++)
#pragma unroll
        for (int j = 0; j < 4; j++) {
            a0[i][j] = (f32x4){0.f, 0.f, 0.f, 0.f};
            a1[i][j] = (f32x4){0.f, 0.f, 0.f, 0.f};
        }
    for (int tap = 0; tap < 16; tap++) {
        int ky = tap >> 2, kx = tap & 3;
        int iy = 2 * ayo - 1 + ky, ix = 2 * axo - 1 + kx;
        bool valid = ((unsigned)iy < 16u) && ((unsigned)ix < 16u);
        int pin = iy * 16 + ix;
        const unsigned short* wh = Wh + ((size_t)(nh * 128 + bn)) * 2048 + tap * 128;
        const unsigned short* wl = Wl + ((size_t)(nh * 128 + bn)) * 2048 + tap * 128;
        for (int c4 = 0; c4 < 4; c4++) {
            // slab layout: granule = (img*16 + slab)*256 + pin
            size_t aoff = (((size_t)img * 16 + c4 * 4 + as) * 256 + pin) * 8;
            __syncthreads();
            uint4 vh = {0, 0, 0, 0}, vl = {0, 0, 0, 0};
            if (valid) {
                vh = *(const uint4*)(h_hi + aoff);
                vl = *(const uint4*)(h_lo + aoff);
            }
            *(uint4*)(Ah + am * 40 + as * 8) = vh;
            *(uint4*)(Al + am * 40 + as * 8) = vl;
            int ci0 = c4 * 32;
#pragma unroll
            for (int u = 0; u < 2; u++) {
                int s = bp * 2 + u;
                *(uint4*)(Bh + bn * 40 + s * 8) = *(const uint4*)(wh + ci0 + s * 8);
                *(uint4*)(Bl + bn * 40 + s * 8) = *(const uint4*)(wl + ci0 + s * 8);
            }
            __syncthreads();
            half8 ah[2], al_[2], bh[4], bl[4];
#pragma unroll
            for (int i = 0; i < 2; i++) {
                ah[i]  = *(const half8*)(Ah + (mw + i * 16 + lc) * 40 + quad * 8);
                al_[i] = *(const half8*)(Al + (mw + i * 16 + lc) * 40 + quad * 8);
            }
#pragma unroll
            for (int j = 0; j < 4; j++) {
                bh[j] = *(const half8*)(Bh + (nw + j * 16 + lc) * 40 + quad * 8);
                bl[j] = *(const half8*)(Bl + (nw + j * 16 + lc) * 40 + quad * 8);
            }
#pragma unroll
            for (int i = 0; i < 2; i++)
#pragma unroll
                for (int j = 0; j < 4; j++) {
                    a0[i][j] = __builtin_amdgcn_mfma_f32_16x16x32_f16(ah[i],  bh[j], a0[i][j], 0, 0, 0);
                    a1[i][j] = __builtin_amdgcn_mfma_f32_16x16x32_f16(ah[i],  bl[j], a1[i][j], 0, 0, 0);
                    a1[i][j] = __builtin_amdgcn_mfma_f32_16x16x32_f16(al_[i], bh[j], a1[i][j], 0, 0, 0);
                }
        }
    }
    const float c1 = 4.8828125e-4f;           // 2^-11
    float bb[4];
#pragma unroll
    for (int j = 0; j < 4; j++) bb[j] = b2[nh * 128 + nw + j * 16 + lc];
#pragma unroll
    for (int i = 0; i < 2; i++)
#pragma unroll
        for (int j = 0; j < 4; j++)
#pragma unroll
            for (int reg = 0; reg < 4; reg++) {
                int px = mw + i * 16 + quad * 4 + reg;
                int co = nh * 128 + nw + j * 16 + lc;
                float v = a0[i][j][reg] + c1 * a1[i][j][reg] + bb[j];
                v = fmaxf(v, 0.f);
                size_t gi = ((size_t)img * 64 + px) * 256 + co;   // [img][px][co]
                fea[gi] = v;              // 16 lanes x 4B contiguous = 64B granule
                fea_bf[gi] = f2bf(v);     // 32B chunks
            }
}

// ---------------- combined codebook (f32 + bf16) ----------------
__global__ __launch_bounds__(256) void k_comb(const float* __restrict__ cb0,
                                              const float* __restrict__ cb1,
                                              const float* __restrict__ cb2,
                                              const int* __restrict__ idxp,
                                              float* __restrict__ C,
                                              unsigned short* __restrict__ Cbf) {
    int i = blockIdx.x * 256 + threadIdx.x;
    int idx = *idxp;
    const float4* lo = (const float4*)cb0;
    const float4* hi = (const float4*)((idx == 2) ? cb2 : ((idx == 1) ? cb1 : cb0));
    float4 v = (i < 32768) ? lo[i] : hi[i - 32768];
    ((float4*)C)[i] = v;
    ushort4 u = { f2bf(v.x), f2bf(v.y), f2bf(v.z), f2bf(v.w) };
    *(ushort4*)(Cbf + (size_t)i * 4) = u;
}

// ---------------- half code norms ----------------
__global__ __launch_bounds__(256) void k_cnorm(const float* __restrict__ C,
                                               const int* __restrict__ idxp,
                                               float* __restrict__ cnorm) {
    int c = blockIdx.x * 256 + threadIdx.x;
    int Kc = (*idxp == 0) ? 512 : 1024;
    if (c >= 1024) return;
    if (c >= Kc) { cnorm[c] = 3.0e38f; return; }
    const float* row = C + (size_t)c * 256;
    double s = 0.0;
    for (int d = 0; d < 256; d++) { double v = row[d]; s += v * v; }
    cnorm[c] = (float)(0.5 * s);
}

// ---------------- VQ screening: bf16 MFMA GEMM + fused top-2/128-codes ----------------
__global__ __launch_bounds__(256) void k_vqg(const unsigned short* __restrict__ fea_bf,
                                             const unsigned short* __restrict__ Cbf,
                                             const float* __restrict__ cnorm,
                                             int* __restrict__ cand) {
    __shared__ char smem[18944];
    unsigned short* As = (unsigned short*)smem;
    unsigned short* Bs = (unsigned short*)(smem + 8192);
    float* t2 = (float*)smem;
    float* t3 = (float*)(smem + 16384);
    int t = threadIdx.x;
    int m0 = blockIdx.x * 128, n0 = blockIdx.y * 128;
    int L = t & 63, w = t >> 6;
    int quad = L >> 4, lc = L & 15;
    int mw = (w >> 1) * 64, nw = (w & 1) * 64;
    f32x4 acc[4][4];
#pragma unroll
    for (int i = 0; i < 4; i++)
#pragma unroll
        for (int j = 0; j < 4; j++) acc[i][j] = (f32x4){0.f, 0.f, 0.f, 0.f};
    for (int k0 = 0; k0 < 256; k0 += 32) {
        __syncthreads();
#pragma unroll
        for (int u = 0; u < 2; u++) {
            int idx = t + u * 256;
            int m = idx >> 2, kq = idx & 3;
            int gm = m0 + m;
            const unsigned short* ga = fea_bf + ((size_t)(gm >> 6) * 64 + (gm & 63)) * 256 + k0 + kq * 8;
            *(uint4*)(As + m * 32 + kq * 8) = *(const uint4*)ga;
            const unsigned short* gb = Cbf + (size_t)(n0 + m) * 256 + k0 + kq * 8;
            *(uint4*)(Bs + m * 32 + kq * 8) = *(const uint4*)gb;
        }
        __syncthreads();
        short8 a[4], bv[4];
#pragma unroll
        for (int i = 0; i < 4; i++)
            a[i] = *(const short8*)(As + (mw + i * 16 + lc) * 32 + quad * 8);
#pragma unroll
        for (int j = 0; j < 4; j++)
            bv[j] = *(const short8*)(Bs + (nw + j * 16 + lc) * 32 + quad * 8);
#pragma unroll
        for (int i = 0; i < 4; i++)
#pragma unroll
            for (int j = 0; j < 4; j++)
                acc[i][j] = __builtin_amdgcn_mfma_f32_16x16x32_bf16(a[i], bv[j], acc[i][j], 0, 0, 0);
    }
    float cn[4];
#pragma unroll
    for (int j = 0; j < 4; j++) cn[j] = cnorm[n0 + nw + j * 16 + lc];
    __syncthreads();
    for (int P = 0; P < 4; P++) {
        if ((w >> 1) == (P >> 1)) {
#pragma unroll
            for (int mi = 0; mi < 2; mi++) {
                int mt = (P & 1) * 2 + mi;
#pragma unroll
                for (int reg = 0; reg < 4; reg++) {
                    int rp = mi * 16 + quad * 4 + reg;
#pragma unroll
                    for (int j = 0; j < 4; j++)
                        t2[rp * 128 + nw + j * 16 + lc] = cn[j] - acc[mt][j][reg];
                }
            }
        }
        __syncthreads();
        if (t < 128) {
            int row = t >> 2, q = t & 3;
            const float* sr = &t2[row * 128 + q * 32];
            float v1 = 3.4e38f, v2 = 3.4e38f; int c1 = 0, c2 = 0;
            for (int e = 0; e < 32; e++) {
                float s = sr[e]; int c = q * 32 + e;
                if (s < v1) { v2 = v1; c2 = c1; v1 = s; c1 = c; }
                else if (s < v2) { v2 = s; c2 = c; }
            }
            float* e3 = &t3[(row * 4 + q) * 4];
            e3[0] = v1; e3[1] = __int_as_float(c1); e3[2] = v2; e3[3] = __int_as_float(c2);
        }
        __syncthreads();
        if (t < 32) {
            float v1 = 3.4e38f, v2 = 3.4e38f; int c1 = 0, c2 = 0;
            for (int q = 0; q < 4; q++) {
                const float* e3 = &t3[(t * 4 + q) * 4];
                float a1 = e3[0]; int a1c = __float_as_int(e3[1]);
                float a2 = e3[2]; int a2c = __float_as_int(e3[3]);
                if (a1 < v1) { v2 = v1; c2 = c1; v1 = a1; c1 = a1c; }
                else if (a1 < v2) { v2 = a1; c2 = a1c; }
                if (a2 < v1) { v2 = v1; c2 = c1; v1 = a2; c1 = a2c; }
                else if (a2 < v2) { v2 = a2; c2 = a2c; }
            }
            size_t row = (size_t)m0 + P * 32 + t;
            cand[row * 16 + blockIdx.y * 2 + 0] = n0 + c1;
            cand[row * 16 + blockIdx.y * 2 + 1] = n0 + c2;
        }
        __syncthreads();
    }
}

// ---------------- exact f64 rescore of 16 candidates/row (fea now [img][px][d]) ----------------
__global__ __launch_bounds__(256) void k_rescore(const float* __restrict__ fea,
                                                 const float* __restrict__ C,
                                                 const int* __restrict__ cand,
                                                 int* __restrict__ enc,
                                                 double* __restrict__ dloss) {
    __shared__ double dsm[256];
    __shared__ int dim_[256];
    __shared__ double bsum[16];
    int t = threadIdx.x;
    int rr = blockIdx.x * 16 + (t >> 4);
    int j = t & 15;
    int c = cand[(size_t)rr * 16 + j];
    const float* row = C + (size_t)c * 256;
    const float* xrow = fea + (size_t)rr * 256;    // rr = chunk-local (img*64+px)
    double s = 0.0;
    for (int d = 0; d < 256; d++) {
        double diff = (double)xrow[d] - (double)row[d];
        s = fma(diff, diff, s);
    }
    dsm[t] = s;
    dim_[t] = c;
    __syncthreads();
    if (j == 0) {
        double best = dsm[t]; int bi = dim_[t];
        for (int q = 1; q < 16; q++) {
            double v = dsm[t + q]; int ci = dim_[t + q];
            if (v < best || (v == best && ci < bi)) { best = v; bi = ci; }
        }
        enc[rr] = bi;
        bsum[t >> 4] = best;
    }
    __syncthreads();
    if (t == 0) {
        double acc = 0.0;
        for (int q = 0; q < 16; q++) acc += bsum[q];
        atomicAdd(dloss, acc);
    }
}

// ---------------- histogram ----------------
__global__ __launch_bounds__(256) void k_hist(const int* __restrict__ enc,
                                              int* __restrict__ counts) {
    __shared__ int hc[1024];
    for (int i = threadIdx.x; i < 1024; i += 256) hc[i] = 0;
    __syncthreads();
    int base = blockIdx.x * 1024;
    for (int i = threadIdx.x; i < 1024; i += 256) atomicAdd(&hc[enc[base + i]], 1);
    __syncthreads();
    for (int i = threadIdx.x; i < 1024; i += 256)
        if (hc[i]) atomicAdd(&counts[i], hc[i]);
}

// ---------------- Wt_bf[n][p][d] = bf16(fc1_w[n][d*64+p]) ----------------
__global__ __launch_bounds__(256) void k_wt(const float* __restrict__ W,
                                            unsigned short* __restrict__ Wt) {
    __shared__ float tile[64][65];
    int n = blockIdx.x;
    int d0 = blockIdx.y * 64;
    int t = threadIdx.x;
    const float* src = W + (size_t)n * 16384 + (size_t)d0 * 64;
#pragma unroll
    for (int u = 0; u < 4; u++) {
        int i = t + u * 256;
        float4 v = ((const float4*)src)[i];
        int dd = i >> 4;
        int p = (i & 15) << 2;
        tile[dd][p] = v.x; tile[dd][p + 1] = v.y; tile[dd][p + 2] = v.z; tile[dd][p + 3] = v.w;
    }
    __syncthreads();
    unsigned short* dst = Wt + (size_t)n * 16384 + d0;
#pragma unroll
    for (int u = 0; u < 4; u++) {
        int i = t + u * 256;
        int p = i >> 4;
        int dd = (i & 15) << 2;
        ushort4 v = { f2bf(tile[dd][p]), f2bf(tile[dd + 1][p]),
                      f2bf(tile[dd + 2][p]), f2bf(tile[dd + 3][p]) };
        *(ushort4*)(dst + (size_t)p * 256 + dd) = v;
    }
}

// ---------------- fc1 bf16 MFMA GEMM with gathered A, split-K z=8 ----------------
__global__ __launch_bounds__(256) void k_fc1g(const int* __restrict__ enc,
                                              const unsigned short* __restrict__ Cbf,
                                              const unsigned short* __restrict__ Wt,
                                              float* __restrict__ part) {
    __shared__ unsigned short As[128 * 32];
    __shared__ unsigned short Bs[128 * 32];
    __shared__ int encs[128];
    int t = threadIdx.x;
    int m0 = blockIdx.x * 128, n0 = blockIdx.y * 128;
    int L = t & 63, w = t >> 6;
    int quad = L >> 4, lc = L & 15;
    int mw = (w >> 1) * 64, nw = (w & 1) * 64;
    f32x4 acc[4][4];
#pragma unroll
    for (int i = 0; i < 4; i++)
#pragma unroll
        for (int j = 0; j < 4; j++) acc[i][j] = (f32x4){0.f, 0.f, 0.f, 0.f};
    int p0 = blockIdx.z * 8;
    for (int p = p0; p < p0 + 8; p++) {
        __syncthreads();
        if (t < 128) encs[t] = enc[(size_t)(m0 + t) * 64 + p];
        __syncthreads();
        for (int dseg = 0; dseg < 256; dseg += 32) {
#pragma unroll
            for (int u = 0; u < 2; u++) {
                int idx = t + u * 256;
                int m = idx >> 2, kq = idx & 3;
                const unsigned short* ga = Cbf + (size_t)encs[m] * 256 + dseg + kq * 8;
                *(uint4*)(As + m * 32 + kq * 8) = *(const uint4*)ga;
                const unsigned short* gb = Wt + (size_t)(n0 + m) * 16384 + p * 256 + dseg + kq * 8;
                *(uint4*)(Bs + m * 32 + kq * 8) = *(const uint4*)gb;
            }
            __syncthreads();
            short8 a[4], bv[4];
#pragma unroll
            for (int i = 0; i < 4; i++)
                a[i] = *(const short8*)(As + (mw + i * 16 + lc) * 32 + quad * 8);
#pragma unroll
            for (int j = 0; j < 4; j++)
                bv[j] = *(const short8*)(Bs + (nw + j * 16 + lc) * 32 + quad * 8);
#pragma unroll
            for (int i = 0; i < 4; i++)
#pragma unroll
                for (int j = 0; j < 4; j++)
                    acc[i][j] = __builtin_amdgcn_mfma_f32_16x16x32_bf16(a[i], bv[j], acc[i][j], 0, 0, 0);
            __syncthreads();
        }
    }
    float* P = part + (size_t)blockIdx.z * (2048 * 512);
#pragma unroll
    for (int i = 0; i < 4; i++)
#pragma unroll
        for (int j = 0; j < 4; j++)
#pragma unroll
            for (int reg = 0; reg < 4; reg++) {
                int row = m0 + mw + i * 16 + quad * 4 + reg;
                int col = n0 + nw + j * 16 + lc;
                P[(size_t)row * 512 + col] = acc[i][j][reg];
            }
}

__global__ __launch_bounds__(256) void k_fc1fin(const float* __restrict__ part,
                                                const float* __restrict__ bias,
                                                float* __restrict__ h1) {
    int i = blockIdx.x * 256 + threadIdx.x;
    float s = 0.f;
#pragma unroll
    for (int z = 0; z < 8; z++) s += part[i + (size_t)z * 1048576];
    s += bias[i & 511];
    h1[i] = 0.5f * s * (1.f + erff(s * 0.70710678118654752f));
}

// ---------------- fc2 ----------------
__global__ __launch_bounds__(256) void k_fc2(const float* __restrict__ h1,
                                             const float* __restrict__ w,
                                             const float* __restrict__ bias,
                                             float* __restrict__ out) {
    int gid = blockIdx.x * 256 + threadIdx.x;
    if (gid >= 20480) return;
    int b = gid / 10, k = gid % 10;
    const float* hr = h1 + (size_t)b * 512;
    const float* wr = w + (size_t)k * 512;
    float acc = bias[k];
#pragma unroll 8
    for (int j = 0; j < 512; j++) acc = fmaf(hr[j], wr[j], acc);
    out[gid] = acc;
}

// ---------------- loss + perplexity ----------------
__global__ __launch_bounds__(256) void k_final(const int* __restrict__ counts,
                                               const double* __restrict__ dloss,
                                               const int* __restrict__ idxp,
                                               float* __restrict__ out) {
    __shared__ float sb[256];
    int t = threadIdx.x;
    int Kc = (*idxp == 0) ? 512 : 1024;
    float local = 0.f;
    for (int c = t; c < Kc; c += 256) {
        float pr = (float)counts[c] * (1.0f / 131072.0f);
        local += pr * logf(pr + 1e-10f);
    }
    sb[t] = local;
    __syncthreads();
    for (int o = 128; o > 0; o >>= 1) {
        if (t < o) sb[t] += sb[t + o];
        __syncthreads();
    }
    if (t == 0) {
        out[20480] = (float)(dloss[0] * 1.25 / (131072.0 * 256.0));
        out[20481] = expf(-sb[0]);
    }
}

extern "C" void kernel_launch(void* const* d_in, const int* in_sizes, int n_in,
                              void* d_out, int out_size, void* d_ws, size_t ws_size,
                              hipStream_t stream) {
    const float* x    = (const float*)d_in[0];
    const int*   idxp = (const int*)d_in[1];
    const float* w1   = (const float*)d_in[2];
    const float* b1   = (const float*)d_in[3];
    const float* w2   = (const float*)d_in[4];
    const float* b2   = (const float*)d_in[5];
    const float* cb0  = (const float*)d_in[6];
    const float* cb1  = (const float*)d_in[7];
    const float* cb2  = (const float*)d_in[8];
    const float* fc1w = (const float*)d_in[9];
    const float* fc1b = (const float*)d_in[10];
    const float* fc2w = (const float*)d_in[11];
    const float* fc2b = (const float*)d_in[12];
    float* out = (float*)d_out;

    char* ws = (char*)d_ws;
    size_t off = 0;
    unsigned short* h_hi   = (unsigned short*)(ws + off); off += (size_t)CHUNK * 256 * 128 * 2; // 16.78 MB
    unsigned short* h_lo   = (unsigned short*)(ws + off); off += (size_t)CHUNK * 256 * 128 * 2; // 16.78 MB
    float*          fea_c  = (float*)(ws + off);          off += (size_t)CHUNK * 16384 * 4;     // 16.78 MB
    unsigned short* fea_bf = (unsigned short*)(ws + off); off += (size_t)CHUNK * 16384 * 2;     //  8.39 MB
    unsigned short* Wt_bf  = (unsigned short*)(ws + off); off += (size_t)512 * 16384 * 2;       // 16.78 MB
    unsigned short* Wc_hi  = (unsigned short*)(ws + off); off += (size_t)256 * 2048 * 2;        //  1.05 MB
    unsigned short* Wc_lo  = (unsigned short*)(ws + off); off += (size_t)256 * 2048 * 2;        //  1.05 MB
    float*          Cc     = (float*)(ws + off);          off += (size_t)1024 * 256 * 4;        //  1.05 MB
    unsigned short* Cc_bf  = (unsigned short*)(ws + off); off += (size_t)1024 * 256 * 2;        //  0.52 MB
    float*          h1     = (float*)(ws + off);          off += (size_t)2048 * 512 * 4;        //  4.19 MB
    int*            cand   = (int*)(ws + off);            off += (size_t)CHUNK * 64 * 16 * 4;   //  1.05 MB
    int*            enc    = (int*)(ws + off);            off += (size_t)131072 * 4;            //  0.52 MB
    float*          cnorm  = (float*)(ws + off);          off += 1024 * 4;
    int*            counts = (int*)(ws + off);            off += 1024 * 4;
    double*         dloss  = (double*)(ws + off);         off += 8;
    // total ~85 MB; part (8*2048*512*4 = 33.55 MB) aliases h_hi+h_lo (dead after chunk loop)
    float* part = (float*)h_hi;

    hipMemsetAsync(counts, 0, 1024 * 4 + 8, stream);   // counts + dloss (contiguous)

    k_comb<<<256, 256, 0, stream>>>(cb0, cb1, cb2, idxp, Cc, Cc_bf);
    k_cnorm<<<4, 256, 0, stream>>>(Cc, idxp, cnorm);
    k_wt<<<dim3(512, 4), 256, 0, stream>>>(fc1w, Wt_bf);
    k_w2p<<<256, 256, 0, stream>>>(w2, Wc_hi, Wc_lo);

    for (int c = 0; c < NCH; c++) {
        k_conv1<<<CHUNK, 256, 0, stream>>>(x + (size_t)c * CHUNK * 3072, w1, b1, h_hi, h_lo);
        k_conv2m<<<dim3(CHUNK, 2), 256, 0, stream>>>(h_hi, h_lo, Wc_hi, Wc_lo, b2, fea_c, fea_bf);
        k_vqg<<<dim3(128, 8), 256, 0, stream>>>(fea_bf, Cc_bf, cnorm, cand);
        k_rescore<<<(CHUNK * 64) / 16, 256, 0, stream>>>(fea_c, Cc, cand,
                                                         enc + (size_t)c * CHUNK * 64, dloss);
    }

    k_hist<<<128, 256, 0, stream>>>(enc, counts);
    k_fc1g<<<dim3(16, 4, 8), 256, 0, stream>>>(enc, Cc_bf, Wt_bf, part);
    k_fc1fin<<<4096, 256, 0, stream>>>(part, fc1b, h1);
    k_fc2<<<80, 256, 0, stream>>>(h1, fc2w, fc2b, out);
    k_final<<<1, 256, 0, stream>>>(counts, dloss, idxp, out);
}

// Round 9
// 1693.900 us; speedup vs baseline: 1.4054x; 1.4054x over previous
//
#include <hip/hip_runtime.h>
#include <hip/hip_bf16.h>
#include <hip/hip_fp16.h>
#include <math.h>

// x:(2048,3,32,32) f32; idx; w1:(128,3,4,4); b1:(128); w2:(256,128,4,4); b2:(256)
// cb0/cb1/cb2:(512,256); fc1_w:(512,16384); fc1_b:(512); fc2_w:(10,512); fc2_b:(10)
// out: 2048*10 logits ++ loss ++ perplexity = 20482 f32
// Precision: conv1 fp32; conv2 split-f16 MFMA (hi + lo*2^-11; lo*lo dropped ~5e-8).
// VQ screening bf16 MFMA + exact f64 rescore of 16 cands. fc1 bf16 MFMA. fc2 fp32.
// R9: conv1 was latency-bound (R8 post-mortem: WRITE fix landed but dur worsened;
// 1 block/CU, 4 waves). Fix = grid.y=4 cg-split -> 16 waves/CU. rescore: 4-way ILP
// f64 accumulation + float4 loads.

#define CHUNK 256
#define NCH 8

typedef __attribute__((ext_vector_type(8))) short short8;            // 8 bf16
typedef __attribute__((ext_vector_type(8))) _Float16 half8;          // 8 f16
typedef __attribute__((ext_vector_type(8))) unsigned short ushort8v;
typedef __attribute__((ext_vector_type(4))) float f32x4;

__device__ inline unsigned short f2bf(float v) {
    __hip_bfloat16 h = __float2bfloat16(v);   // RNE
    return *reinterpret_cast<unsigned short*>(&h);
}

// ---------------- conv1: fp32; grid (CHUNK,4): block = (image, 4-of-16 cg) ----------------
// Emits split-f16 h, slab layout [b][cg][px][8ci] (lane-contiguous 16B stores).
__global__ __launch_bounds__(256) void k_conv1(const float* __restrict__ x,
                                               const float* __restrict__ w1,
                                               const float* __restrict__ b1,
                                               unsigned short* __restrict__ h_hi,
                                               unsigned short* __restrict__ h_lo) {
    __shared__ float xs[3 * 32 * 32];
    int b = blockIdx.x, yg = blockIdx.y, t = threadIdx.x;
    const float* xb = x + (size_t)b * 3072;
    for (int i = t; i < 768; i += 256)
        ((float4*)xs)[i] = ((const float4*)xb)[i];
    __syncthreads();
    int py = t >> 4, px = t & 15;
    float win[48];
#pragma unroll
    for (int ci = 0; ci < 3; ci++)
#pragma unroll
        for (int ky = 0; ky < 4; ky++) {
            int iy = 2 * py - 1 + ky;
#pragma unroll
            for (int kx = 0; kx < 4; kx++) {
                int ix = 2 * px - 1 + kx;
                bool ok = ((unsigned)iy < 32u) && ((unsigned)ix < 32u);
                win[ci * 16 + ky * 4 + kx] = ok ? xs[ci * 1024 + iy * 32 + ix] : 0.f;
            }
        }
#pragma unroll 1
    for (int cg = yg * 4; cg < yg * 4 + 4; cg++) {
        ushort8v hi8, lo8;
#pragma unroll
        for (int j = 0; j < 8; j++) {
            int co = cg * 8 + j;
            const float* w = w1 + co * 48;    // wave-uniform -> scalar K$ loads
            float acc = b1[co];
#pragma unroll
            for (int q = 0; q < 48; q++) acc = fmaf(win[q], w[q], acc);
            float v = fmaxf(acc, 0.f);
            __half hh = __float2half(v);
            float hf = __half2float(hh);
            __half ll = __float2half((v - hf) * 2048.0f);   // lo scaled 2^11: normal range
            hi8[j] = __half_as_ushort(hh);
            lo8[j] = __half_as_ushort(ll);
        }
        size_t go = (((size_t)b * 16 + cg) * 256 + t) * 8;
        *(ushort8v*)(h_hi + go) = hi8;
        *(ushort8v*)(h_lo + go) = lo8;
    }
}

// ---------------- w2 prep: [co][ci][tap] -> split-f16 [co][tap][ci] ----------------
__global__ __launch_bounds__(256) void k_w2p(const float* __restrict__ w2,
                                             unsigned short* __restrict__ Wh,
                                             unsigned short* __restrict__ Wl) {
    int co = blockIdx.x, t = threadIdx.x;
#pragma unroll
    for (int k = 0; k < 8; k++) {
        int e = t + k * 256;                  // 0..2047
        int ci = e >> 4, tap = e & 15;
        float v = w2[(size_t)co * 2048 + e];
        __half hh = __float2half(v);
        __half ll = __float2half((v - __half2float(hh)) * 2048.0f);
        Wh[(size_t)co * 2048 + tap * 128 + ci] = __half_as_ushort(hh);
        Wl[(size_t)co * 2048 + tap * 128 + ci] = __half_as_ushort(ll);
    }
}

// ---------------- conv2 as split-f16 MFMA im2col GEMM ----------------
__global__ __launch_bounds__(256, 2) void k_conv2m(const unsigned short* __restrict__ h_hi,
                                                   const unsigned short* __restrict__ h_lo,
                                                   const unsigned short* __restrict__ Wh,
                                                   const unsigned short* __restrict__ Wl,
                                                   const float* __restrict__ b2,
                                                   float* __restrict__ fea,
                                                   unsigned short* __restrict__ fea_bf) {
    __shared__ unsigned short Ah[64 * 40], Al[64 * 40], Bh[128 * 40], Bl[128 * 40];  // 30 KB
    int img = blockIdx.x, nh = blockIdx.y, t = threadIdx.x;
    int L = t & 63, w = t >> 6;
    int quad = L >> 4, lc = L & 15;
    int mw = (w >> 1) * 32, nw = (w & 1) * 64;
    int am = t >> 2, as = t & 3;
    int ayo = am >> 3, axo = am & 7;
    int bn = t >> 1, bp = t & 1;
    f32x4 a0[2][4], a1[2][4];
#pragma unroll
    for (int i = 0; i < 2; i++)
#pragma unroll
        for (int j = 0; j < 4; j++) {
            a0[i][j] = (f32x4){0.f, 0.f, 0.f, 0.f};
            a1[i][j] = (f32x4){0.f, 0.f, 0.f, 0.f};
        }
    for (int tap = 0; tap < 16; tap++) {
        int ky = tap >> 2, kx = tap & 3;
        int iy = 2 * ayo - 1 + ky, ix = 2 * axo - 1 + kx;
        bool valid = ((unsigned)iy < 16u) && ((unsigned)ix < 16u);
        int pin = iy * 16 + ix;
        const unsigned short* wh = Wh + ((size_t)(nh * 128 + bn)) * 2048 + tap * 128;
        const unsigned short* wl = Wl + ((size_t)(nh * 128 + bn)) * 2048 + tap * 128;
        for (int c4 = 0; c4 < 4; c4++) {
            size_t aoff = (((size_t)img * 16 + c4 * 4 + as) * 256 + pin) * 8;
            __syncthreads();
            uint4 vh = {0, 0, 0, 0}, vl = {0, 0, 0, 0};
            if (valid) {
                vh = *(const uint4*)(h_hi + aoff);
                vl = *(const uint4*)(h_lo + aoff);
            }
            *(uint4*)(Ah + am * 40 + as * 8) = vh;
            *(uint4*)(Al + am * 40 + as * 8) = vl;
            int ci0 = c4 * 32;
#pragma unroll
            for (int u = 0; u < 2; u++) {
                int s = bp * 2 + u;
                *(uint4*)(Bh + bn * 40 + s * 8) = *(const uint4*)(wh + ci0 + s * 8);
                *(uint4*)(Bl + bn * 40 + s * 8) = *(const uint4*)(wl + ci0 + s * 8);
            }
            __syncthreads();
            half8 ah[2], al_[2], bh[4], bl[4];
#pragma unroll
            for (int i = 0; i < 2; i++) {
                ah[i]  = *(const half8*)(Ah + (mw + i * 16 + lc) * 40 + quad * 8);
                al_[i] = *(const half8*)(Al + (mw + i * 16 + lc) * 40 + quad * 8);
            }
#pragma unroll
            for (int j = 0; j < 4; j++) {
                bh[j] = *(const half8*)(Bh + (nw + j * 16 + lc) * 40 + quad * 8);
                bl[j] = *(const half8*)(Bl + (nw + j * 16 + lc) * 40 + quad * 8);
            }
#pragma unroll
            for (int i = 0; i < 2; i++)
#pragma unroll
                for (int j = 0; j < 4; j++) {
                    a0[i][j] = __builtin_amdgcn_mfma_f32_16x16x32_f16(ah[i],  bh[j], a0[i][j], 0, 0, 0);
                    a1[i][j] = __builtin_amdgcn_mfma_f32_16x16x32_f16(ah[i],  bl[j], a1[i][j], 0, 0, 0);
                    a1[i][j] = __builtin_amdgcn_mfma_f32_16x16x32_f16(al_[i], bh[j], a1[i][j], 0, 0, 0);
                }
        }
    }
    const float c1 = 4.8828125e-4f;           // 2^-11
    float bb[4];
#pragma unroll
    for (int j = 0; j < 4; j++) bb[j] = b2[nh * 128 + nw + j * 16 + lc];
#pragma unroll
    for (int i = 0; i < 2; i++)
#pragma unroll
        for (int j = 0; j < 4; j++)
#pragma unroll
            for (int reg = 0; reg < 4; reg++) {
                int px = mw + i * 16 + quad * 4 + reg;
                int co = nh * 128 + nw + j * 16 + lc;
                float v = a0[i][j][reg] + c1 * a1[i][j][reg] + bb[j];
                v = fmaxf(v, 0.f);
                size_t gi = ((size_t)img * 64 + px) * 256 + co;   // [img][px][co]
                fea[gi] = v;
                fea_bf[gi] = f2bf(v);
            }
}

// ---------------- combined codebook (f32 + bf16) ----------------
__global__ __launch_bounds__(256) void k_comb(const float* __restrict__ cb0,
                                              const float* __restrict__ cb1,
                                              const float* __restrict__ cb2,
                                              const int* __restrict__ idxp,
                                              float* __restrict__ C,
                                              unsigned short* __restrict__ Cbf) {
    int i = blockIdx.x * 256 + threadIdx.x;
    int idx = *idxp;
    const float4* lo = (const float4*)cb0;
    const float4* hi = (const float4*)((idx == 2) ? cb2 : ((idx == 1) ? cb1 : cb0));
    float4 v = (i < 32768) ? lo[i] : hi[i - 32768];
    ((float4*)C)[i] = v;
    ushort4 u = { f2bf(v.x), f2bf(v.y), f2bf(v.z), f2bf(v.w) };
    *(ushort4*)(Cbf + (size_t)i * 4) = u;
}

// ---------------- half code norms ----------------
__global__ __launch_bounds__(256) void k_cnorm(const float* __restrict__ C,
                                               const int* __restrict__ idxp,
                                               float* __restrict__ cnorm) {
    int c = blockIdx.x * 256 + threadIdx.x;
    int Kc = (*idxp == 0) ? 512 : 1024;
    if (c >= 1024) return;
    if (c >= Kc) { cnorm[c] = 3.0e38f; return; }
    const float* row = C + (size_t)c * 256;
    double s = 0.0;
    for (int d = 0; d < 256; d++) { double v = row[d]; s += v * v; }
    cnorm[c] = (float)(0.5 * s);
}

// ---------------- VQ screening: bf16 MFMA GEMM + fused top-2/128-codes ----------------
__global__ __launch_bounds__(256) void k_vqg(const unsigned short* __restrict__ fea_bf,
                                             const unsigned short* __restrict__ Cbf,
                                             const float* __restrict__ cnorm,
                                             int* __restrict__ cand) {
    __shared__ char smem[18944];
    unsigned short* As = (unsigned short*)smem;
    unsigned short* Bs = (unsigned short*)(smem + 8192);
    float* t2 = (float*)smem;
    float* t3 = (float*)(smem + 16384);
    int t = threadIdx.x;
    int m0 = blockIdx.x * 128, n0 = blockIdx.y * 128;
    int L = t & 63, w = t >> 6;
    int quad = L >> 4, lc = L & 15;
    int mw = (w >> 1) * 64, nw = (w & 1) * 64;
    f32x4 acc[4][4];
#pragma unroll
    for (int i = 0; i < 4; i++)
#pragma unroll
        for (int j = 0; j < 4; j++) acc[i][j] = (f32x4){0.f, 0.f, 0.f, 0.f};
    for (int k0 = 0; k0 < 256; k0 += 32) {
        __syncthreads();
#pragma unroll
        for (int u = 0; u < 2; u++) {
            int idx = t + u * 256;
            int m = idx >> 2, kq = idx & 3;
            int gm = m0 + m;
            const unsigned short* ga = fea_bf + ((size_t)(gm >> 6) * 64 + (gm & 63)) * 256 + k0 + kq * 8;
            *(uint4*)(As + m * 32 + kq * 8) = *(const uint4*)ga;
            const unsigned short* gb = Cbf + (size_t)(n0 + m) * 256 + k0 + kq * 8;
            *(uint4*)(Bs + m * 32 + kq * 8) = *(const uint4*)gb;
        }
        __syncthreads();
        short8 a[4], bv[4];
#pragma unroll
        for (int i = 0; i < 4; i++)
            a[i] = *(const short8*)(As + (mw + i * 16 + lc) * 32 + quad * 8);
#pragma unroll
        for (int j = 0; j < 4; j++)
            bv[j] = *(const short8*)(Bs + (nw + j * 16 + lc) * 32 + quad * 8);
#pragma unroll
        for (int i = 0; i < 4; i++)
#pragma unroll
            for (int j = 0; j < 4; j++)
                acc[i][j] = __builtin_amdgcn_mfma_f32_16x16x32_bf16(a[i], bv[j], acc[i][j], 0, 0, 0);
    }
    float cn[4];
#pragma unroll
    for (int j = 0; j < 4; j++) cn[j] = cnorm[n0 + nw + j * 16 + lc];
    __syncthreads();
    for (int P = 0; P < 4; P++) {
        if ((w >> 1) == (P >> 1)) {
#pragma unroll
            for (int mi = 0; mi < 2; mi++) {
                int mt = (P & 1) * 2 + mi;
#pragma unroll
                for (int reg = 0; reg < 4; reg++) {
                    int rp = mi * 16 + quad * 4 + reg;
#pragma unroll
                    for (int j = 0; j < 4; j++)
                        t2[rp * 128 + nw + j * 16 + lc] = cn[j] - acc[mt][j][reg];
                }
            }
        }
        __syncthreads();
        if (t < 128) {
            int row = t >> 2, q = t & 3;
            const float* sr = &t2[row * 128 + q * 32];
            float v1 = 3.4e38f, v2 = 3.4e38f; int c1 = 0, c2 = 0;
            for (int e = 0; e < 32; e++) {
                float s = sr[e]; int c = q * 32 + e;
                if (s < v1) { v2 = v1; c2 = c1; v1 = s; c1 = c; }
                else if (s < v2) { v2 = s; c2 = c; }
            }
            float* e3 = &t3[(row * 4 + q) * 4];
            e3[0] = v1; e3[1] = __int_as_float(c1); e3[2] = v2; e3[3] = __int_as_float(c2);
        }
        __syncthreads();
        if (t < 32) {
            float v1 = 3.4e38f, v2 = 3.4e38f; int c1 = 0, c2 = 0;
            for (int q = 0; q < 4; q++) {
                const float* e3 = &t3[(t * 4 + q) * 4];
                float a1 = e3[0]; int a1c = __float_as_int(e3[1]);
                float a2 = e3[2]; int a2c = __float_as_int(e3[3]);
                if (a1 < v1) { v2 = v1; c2 = c1; v1 = a1; c1 = a1c; }
                else if (a1 < v2) { v2 = a1; c2 = a1c; }
                if (a2 < v1) { v2 = v1; c2 = c1; v1 = a2; c1 = a2c; }
                else if (a2 < v2) { v2 = a2; c2 = a2c; }
            }
            size_t row = (size_t)m0 + P * 32 + t;
            cand[row * 16 + blockIdx.y * 2 + 0] = n0 + c1;
            cand[row * 16 + blockIdx.y * 2 + 1] = n0 + c2;
        }
        __syncthreads();
    }
}

// ---------------- exact f64 rescore, 4-way ILP + float4 loads ----------------
__global__ __launch_bounds__(256) void k_rescore(const float* __restrict__ fea,
                                                 const float* __restrict__ C,
                                                 const int* __restrict__ cand,
                                                 int* __restrict__ enc,
                                                 double* __restrict__ dloss) {
    __shared__ double dsm[256];
    __shared__ int dim_[256];
    __shared__ double bsum[16];
    int t = threadIdx.x;
    int rr = blockIdx.x * 16 + (t >> 4);
    int j = t & 15;
    int c = cand[(size_t)rr * 16 + j];
    const float* row = C + (size_t)c * 256;
    const float* xrow = fea + (size_t)rr * 256;    // rr = chunk-local (img*64+px)
    double s0 = 0.0, s1 = 0.0, s2 = 0.0, s3 = 0.0;
#pragma unroll 4
    for (int d = 0; d < 256; d += 4) {
        float4 xv = *(const float4*)(xrow + d);
        float4 cv = *(const float4*)(row + d);
        double d0 = (double)xv.x - (double)cv.x;
        double d1 = (double)xv.y - (double)cv.y;
        double d2 = (double)xv.z - (double)cv.z;
        double d3 = (double)xv.w - (double)cv.w;
        s0 = fma(d0, d0, s0);
        s1 = fma(d1, d1, s1);
        s2 = fma(d2, d2, s2);
        s3 = fma(d3, d3, s3);
    }
    double s = (s0 + s1) + (s2 + s3);
    dsm[t] = s;
    dim_[t] = c;
    __syncthreads();
    if (j == 0) {
        double best = dsm[t]; int bi = dim_[t];
        for (int q = 1; q < 16; q++) {
            double v = dsm[t + q]; int ci = dim_[t + q];
            if (v < best || (v == best && ci < bi)) { best = v; bi = ci; }
        }
        enc[rr] = bi;
        bsum[t >> 4] = best;
    }
    __syncthreads();
    if (t == 0) {
        double acc = 0.0;
        for (int q = 0; q < 16; q++) acc += bsum[q];
        atomicAdd(dloss, acc);
    }
}

// ---------------- histogram ----------------
__global__ __launch_bounds__(256) void k_hist(const int* __restrict__ enc,
                                              int* __restrict__ counts) {
    __shared__ int hc[1024];
    for (int i = threadIdx.x; i < 1024; i += 256) hc[i] = 0;
    __syncthreads();
    int base = blockIdx.x * 1024;
    for (int i = threadIdx.x; i < 1024; i += 256) atomicAdd(&hc[enc[base + i]], 1);
    __syncthreads();
    for (int i = threadIdx.x; i < 1024; i += 256)
        if (hc[i]) atomicAdd(&counts[i], hc[i]);
}

// ---------------- Wt_bf[n][p][d] = bf16(fc1_w[n][d*64+p]) ----------------
__global__ __launch_bounds__(256) void k_wt(const float* __restrict__ W,
                                            unsigned short* __restrict__ Wt) {
    __shared__ float tile[64][65];
    int n = blockIdx.x;
    int d0 = blockIdx.y * 64;
    int t = threadIdx.x;
    const float* src = W + (size_t)n * 16384 + (size_t)d0 * 64;
#pragma unroll
    for (int u = 0; u < 4; u++) {
        int i = t + u * 256;
        float4 v = ((const float4*)src)[i];
        int dd = i >> 4;
        int p = (i & 15) << 2;
        tile[dd][p] = v.x; tile[dd][p + 1] = v.y; tile[dd][p + 2] = v.z; tile[dd][p + 3] = v.w;
    }
    __syncthreads();
    unsigned short* dst = Wt + (size_t)n * 16384 + d0;
#pragma unroll
    for (int u = 0; u < 4; u++) {
        int i = t + u * 256;
        int p = i >> 4;
        int dd = (i & 15) << 2;
        ushort4 v = { f2bf(tile[dd][p]), f2bf(tile[dd + 1][p]),
                      f2bf(tile[dd + 2][p]), f2bf(tile[dd + 3][p]) };
        *(ushort4*)(dst + (size_t)p * 256 + dd) = v;
    }
}

// ---------------- fc1 bf16 MFMA GEMM with gathered A, split-K z=8 ----------------
__global__ __launch_bounds__(256) void k_fc1g(const int* __restrict__ enc,
                                              const unsigned short* __restrict__ Cbf,
                                              const unsigned short* __restrict__ Wt,
                                              float* __restrict__ part) {
    __shared__ unsigned short As[128 * 32];
    __shared__ unsigned short Bs[128 * 32];
    __shared__ int encs[128];
    int t = threadIdx.x;
    int m0 = blockIdx.x * 128, n0 = blockIdx.y * 128;
    int L = t & 63, w = t >> 6;
    int quad = L >> 4, lc = L & 15;
    int mw = (w >> 1) * 64, nw = (w & 1) * 64;
    f32x4 acc[4][4];
#pragma unroll
    for (int i = 0; i < 4; i++)
#pragma unroll
        for (int j = 0; j < 4; j++) acc[i][j] = (f32x4){0.f, 0.f, 0.f, 0.f};
    int p0 = blockIdx.z * 8;
    for (int p = p0; p < p0 + 8; p++) {
        __syncthreads();
        if (t < 128) encs[t] = enc[(size_t)(m0 + t) * 64 + p];
        __syncthreads();
        for (int dseg = 0; dseg < 256; dseg += 32) {
#pragma unroll
            for (int u = 0; u < 2; u++) {
                int idx = t + u * 256;
                int m = idx >> 2, kq = idx & 3;
                const unsigned short* ga = Cbf + (size_t)encs[m] * 256 + dseg + kq * 8;
                *(uint4*)(As + m * 32 + kq * 8) = *(const uint4*)ga;
                const unsigned short* gb = Wt + (size_t)(n0 + m) * 16384 + p * 256 + dseg + kq * 8;
                *(uint4*)(Bs + m * 32 + kq * 8) = *(const uint4*)gb;
            }
            __syncthreads();
            short8 a[4], bv[4];
#pragma unroll
            for (int i = 0; i < 4; i++)
                a[i] = *(const short8*)(As + (mw + i * 16 + lc) * 32 + quad * 8);
#pragma unroll
            for (int j = 0; j < 4; j++)
                bv[j] = *(const short8*)(Bs + (nw + j * 16 + lc) * 32 + quad * 8);
#pragma unroll
            for (int i = 0; i < 4; i++)
#pragma unroll
                for (int j = 0; j < 4; j++)
                    acc[i][j] = __builtin_amdgcn_mfma_f32_16x16x32_bf16(a[i], bv[j], acc[i][j], 0, 0, 0);
            __syncthreads();
        }
    }
    float* P = part + (size_t)blockIdx.z * (2048 * 512);
#pragma unroll
    for (int i = 0; i < 4; i++)
#pragma unroll
        for (int j = 0; j < 4; j++)
#pragma unroll
            for (int reg = 0; reg < 4; reg++) {
                int row = m0 + mw + i * 16 + quad * 4 + reg;
                int col = n0 + nw + j * 16 + lc;
                P[(size_t)row * 512 + col] = acc[i][j][reg];
            }
}

__global__ __launch_bounds__(256) void k_fc1fin(const float* __restrict__ part,
                                                const float* __restrict__ bias,
                                                float* __restrict__ h1) {
    int i = blockIdx.x * 256 + threadIdx.x;
    float s = 0.f;
#pragma unroll
    for (int z = 0; z < 8; z++) s += part[i + (size_t)z * 1048576];
    s += bias[i & 511];
    h1[i] = 0.5f * s * (1.f + erff(s * 0.70710678118654752f));
}

// ---------------- fc2 ----------------
__global__ __launch_bounds__(256) void k_fc2(const float* __restrict__ h1,
                                             const float* __restrict__ w,
                                             const float* __restrict__ bias,
                                             float* __restrict__ out) {
    int gid = blockIdx.x * 256 + threadIdx.x;
    if (gid >= 20480) return;
    int b = gid / 10, k = gid % 10;
    const float* hr = h1 + (size_t)b * 512;
    const float* wr = w + (size_t)k * 512;
    float acc = bias[k];
#pragma unroll 8
    for (int j = 0; j < 512; j++) acc = fmaf(hr[j], wr[j], acc);
    out[gid] = acc;
}

// ---------------- loss + perplexity ----------------
__global__ __launch_bounds__(256) void k_final(const int* __restrict__ counts,
                                               const double* __restrict__ dloss,
                                               const int* __restrict__ idxp,
                                               float* __restrict__ out) {
    __shared__ float sb[256];
    int t = threadIdx.x;
    int Kc = (*idxp == 0) ? 512 : 1024;
    float local = 0.f;
    for (int c = t; c < Kc; c += 256) {
        float pr = (float)counts[c] * (1.0f / 131072.0f);
        local += pr * logf(pr + 1e-10f);
    }
    sb[t] = local;
    __syncthreads();
    for (int o = 128; o > 0; o >>= 1) {
        if (t < o) sb[t] += sb[t + o];
        __syncthreads();
    }
    if (t == 0) {
        out[20480] = (float)(dloss[0] * 1.25 / (131072.0 * 256.0));
        out[20481] = expf(-sb[0]);
    }
}

extern "C" void kernel_launch(void* const* d_in, const int* in_sizes, int n_in,
                              void* d_out, int out_size, void* d_ws, size_t ws_size,
                              hipStream_t stream) {
    const float* x    = (const float*)d_in[0];
    const int*   idxp = (const int*)d_in[1];
    const float* w1   = (const float*)d_in[2];
    const float* b1   = (const float*)d_in[3];
    const float* w2   = (const float*)d_in[4];
    const float* b2   = (const float*)d_in[5];
    const float* cb0  = (const float*)d_in[6];
    const float* cb1  = (const float*)d_in[7];
    const float* cb2  = (const float*)d_in[8];
    const float* fc1w = (const float*)d_in[9];
    const float* fc1b = (const float*)d_in[10];
    const float* fc2w = (const float*)d_in[11];
    const float* fc2b = (const float*)d_in[12];
    float* out = (float*)d_out;

    char* ws = (char*)d_ws;
    size_t off = 0;
    unsigned short* h_hi   = (unsigned short*)(ws + off); off += (size_t)CHUNK * 256 * 128 * 2; // 16.78 MB
    unsigned short* h_lo   = (unsigned short*)(ws + off); off += (size_t)CHUNK * 256 * 128 * 2; // 16.78 MB
    float*          fea_c  = (float*)(ws + off);          off += (size_t)CHUNK * 16384 * 4;     // 16.78 MB
    unsigned short* fea_bf = (unsigned short*)(ws + off); off += (size_t)CHUNK * 16384 * 2;     //  8.39 MB
    unsigned short* Wt_bf  = (unsigned short*)(ws + off); off += (size_t)512 * 16384 * 2;       // 16.78 MB
    unsigned short* Wc_hi  = (unsigned short*)(ws + off); off += (size_t)256 * 2048 * 2;        //  1.05 MB
    unsigned short* Wc_lo  = (unsigned short*)(ws + off); off += (size_t)256 * 2048 * 2;        //  1.05 MB
    float*          Cc     = (float*)(ws + off);          off += (size_t)1024 * 256 * 4;        //  1.05 MB
    unsigned short* Cc_bf  = (unsigned short*)(ws + off); off += (size_t)1024 * 256 * 2;        //  0.52 MB
    float*          h1     = (float*)(ws + off);          off += (size_t)2048 * 512 * 4;        //  4.19 MB
    int*            cand   = (int*)(ws + off);            off += (size_t)CHUNK * 64 * 16 * 4;   //  1.05 MB
    int*            enc    = (int*)(ws + off);            off += (size_t)131072 * 4;            //  0.52 MB
    float*          cnorm  = (float*)(ws + off);          off += 1024 * 4;
    int*            counts = (int*)(ws + off);            off += 1024 * 4;
    double*         dloss  = (double*)(ws + off);         off += 8;
    // total ~85 MB; part (33.55 MB) aliases h_hi+h_lo (dead after chunk loop)
    float* part = (float*)h_hi;

    hipMemsetAsync(counts, 0, 1024 * 4 + 8, stream);   // counts + dloss (contiguous)

    k_comb<<<256, 256, 0, stream>>>(cb0, cb1, cb2, idxp, Cc, Cc_bf);
    k_cnorm<<<4, 256, 0, stream>>>(Cc, idxp, cnorm);
    k_wt<<<dim3(512, 4), 256, 0, stream>>>(fc1w, Wt_bf);
    k_w2p<<<256, 256, 0, stream>>>(w2, Wc_hi, Wc_lo);

    for (int c = 0; c < NCH; c++) {
        k_conv1<<<dim3(CHUNK, 4), 256, 0, stream>>>(x + (size_t)c * CHUNK * 3072, w1, b1, h_hi, h_lo);
        k_conv2m<<<dim3(CHUNK, 2), 256, 0, stream>>>(h_hi, h_lo, Wc_hi, Wc_lo, b2, fea_c, fea_bf);
        k_vqg<<<dim3(128, 8), 256, 0, stream>>>(fea_bf, Cc_bf, cnorm, cand);
        k_rescore<<<(CHUNK * 64) / 16, 256, 0, stream>>>(fea_c, Cc, cand,
                                                         enc + (size_t)c * CHUNK * 64, dloss);
    }

    k_hist<<<128, 256, 0, stream>>>(enc, counts);
    k_fc1g<<<dim3(16, 4, 8), 256, 0, stream>>>(enc, Cc_bf, Wt_bf, part);
    k_fc1fin<<<4096, 256, 0, stream>>>(part, fc1b, h1);
    k_fc2<<<80, 256, 0, stream>>>(h1, fc2w, fc2b, out);
    k_final<<<1, 256, 0, stream>>>(counts, dloss, idxp, out);
}